// Round 2
// baseline (2018.285 us; speedup 1.0000x reference)
//
#include <hip/hip_runtime.h>
#include <stdint.h>

typedef unsigned char u8;

#define CDIM  128
#define KNBR  48
#define HEADS 8
#define DHEAD 16
#define FFDIM 256
#define OUTD  128

// ---------------------------------------------------------------------------
// K0: probe key_mask storage. If stored as int32 (0/1), all bytes at pos%4!=0
// are zero. If stored as u8 bool, ~20% of them are 1. Scans N*K bytes, which
// is in-bounds under either interpretation. flag=1 -> u8 storage.
// ---------------------------------------------------------------------------
__global__ void k_mask_probe(const unsigned int* __restrict__ mw, int nwords,
                             int* __restrict__ flag)
{
    unsigned int any = 0;
    for (int j = blockIdx.x * blockDim.x + threadIdx.x; j < nwords;
         j += gridDim.x * blockDim.x)
        any |= mw[j] & 0xFFFFFF00u;
    if (any) atomicOr(flag, 1);
}

// ---------------------------------------------------------------------------
// K1: QKV projection.  QKV = F @ in_proj_w^T + in_proj_b, split into Q/Fk/Fv.
// Block: 384 threads (one output column each), 8 rows per block.
// ---------------------------------------------------------------------------
__global__ __launch_bounds__(384) void k_qkv(
    const float* __restrict__ F, const float* __restrict__ W,
    const float* __restrict__ B,
    float* __restrict__ Q, float* __restrict__ Fk, float* __restrict__ Fv, int N)
{
    __shared__ float xL[8][CDIM];
    int row0 = blockIdx.x * 8;
    int t = threadIdx.x;
    for (int o = t; o < 8 * CDIM; o += 384) {
        int r = o >> 7, c = o & 127;
        int row = row0 + r;
        xL[r][c] = (row < N) ? F[row * CDIM + c] : 0.f;
    }
    __syncthreads();

    int e = t;  // 0..383
    const float4* W4 = (const float4*)(W + e * CDIM);
    float acc[8] = {0.f,0.f,0.f,0.f,0.f,0.f,0.f,0.f};
    #pragma unroll 8
    for (int c4 = 0; c4 < CDIM / 4; ++c4) {
        float4 w = W4[c4];
        #pragma unroll
        for (int r = 0; r < 8; ++r) {
            const float* x = &xL[r][c4 * 4];
            acc[r] += x[0]*w.x + x[1]*w.y + x[2]*w.z + x[3]*w.w;
        }
    }
    float bv = B[e];
    float* dst; int eo;
    if (e < 128)      { dst = Q;  eo = e; }
    else if (e < 256) { dst = Fk; eo = e - 128; }
    else              { dst = Fv; eo = e - 256; }
    #pragma unroll
    for (int r = 0; r < 8; ++r) {
        int row = row0 + r;
        if (row < N) dst[row * CDIM + eo] = acc[r] + bv;
    }
}

// ---------------------------------------------------------------------------
// K2: attention, one block (256 thr) per query voxel.
//   score[h,k] = ( q_h . Fk[idx_k]_h  +  qw[h,:] . P[k,:] ) / 4
//   ctx[h,:]   = sum_k a[h,k] Fv[idx_k]_h  +  Pbar[h,:] @ wv_h^T
// ---------------------------------------------------------------------------
__global__ __launch_bounds__(256) void k_attn(
    const float* __restrict__ coords, const int* __restrict__ kidx,
    const u8* __restrict__ kmask_u8, const int* __restrict__ kmask_i32,
    const int* __restrict__ maskflag,
    const float* __restrict__ Q, const float* __restrict__ Fk,
    const float* __restrict__ Fv,
    const float* __restrict__ wk, const float* __restrict__ wv,
    const float* __restrict__ kpw, const float* __restrict__ kpb,
    float* __restrict__ CTX)
{
    __shared__ float Pl[KNBR][CDIM + 4];     // pos embedding (padded: bank spread)
    __shared__ float Gl[KNBR][CDIM + 4];     // gathered Fk, then Fv
    __shared__ float qwl[HEADS][CDIM + 4];   // q_h @ wk_slice
    __shared__ float Pbar[HEADS][CDIM + 4];  // attn-weighted P
    __shared__ float Ql[CDIM];
    __shared__ float scL[HEADS][KNBR];
    __shared__ float rel[KNBR][3];
    __shared__ int   idxl[KNBR];
    __shared__ int   mskl[KNBR];

    int n = blockIdx.x;
    int t = threadIdx.x;

    // phase 1: indices / mask / q row
    if (t < KNBR) {
        idxl[t] = kidx[n * KNBR + t];
        mskl[t] = maskflag[0] ? (int)kmask_u8[n * KNBR + t]
                              : kmask_i32[n * KNBR + t];
    } else if (t >= 128 && t < 256) {
        Ql[t - 128] = Q[n * CDIM + (t - 128)];
    }
    __syncthreads();

    // phase 2: rel coords, gather Fk, qw
    for (int o = t; o < KNBR * CDIM; o += 256) {
        int k = o >> 7, c = o & 127;
        Gl[k][c] = Fk[idxl[k] * CDIM + c];
    }
    if (t < KNBR * 3) {
        int k = t / 3, d = t % 3;
        rel[k][d] = coords[idxl[k] * 3 + d] - coords[n * 3 + d];
    }
    for (int o = t; o < HEADS * CDIM; o += 256) {
        int h = o >> 7, c = o & 127;
        float s = 0.f;
        #pragma unroll
        for (int d = 0; d < DHEAD; ++d)
            s += Ql[h * DHEAD + d] * wk[(h * DHEAD + d) * CDIM + c];
        qwl[h][c] = s;
    }
    __syncthreads();

    // phase 3: positional embedding P = relu(rel . kpw^T + kpb)
    for (int o = t; o < KNBR * CDIM; o += 256) {
        int k = o >> 7, c = o & 127;
        float s = kpb[c] + rel[k][0] * kpw[c * 3]
                         + rel[k][1] * kpw[c * 3 + 1]
                         + rel[k][2] * kpw[c * 3 + 2];
        Pl[k][c] = fmaxf(s, 0.f);
    }
    __syncthreads();

    // phase 4: scores
    for (int o = t; o < HEADS * KNBR; o += 256) {
        int k = o >> 3, h = o & 7;
        float s = 0.f;
        #pragma unroll
        for (int d = 0; d < DHEAD; ++d)
            s += Ql[h * DHEAD + d] * Gl[k][h * DHEAD + d];
        #pragma unroll 8
        for (int c = 0; c < CDIM; ++c)
            s += qwl[h][c] * Pl[k][c];
        scL[h][k] = mskl[k] ? -1e30f : s * 0.25f;
    }
    __syncthreads();

    // phase 5: softmax (32 lanes per head; exp(-1e30-m)==0 exactly matches ref mask)
    {
        int h = t >> 5, lane = t & 31;
        float v0 = scL[h][lane];
        float v1 = (lane + 32 < KNBR) ? scL[h][lane + 32] : -1e30f;
        float m = fmaxf(v0, v1);
        #pragma unroll
        for (int off = 16; off >= 1; off >>= 1)
            m = fmaxf(m, __shfl_xor(m, off, 32));
        float e0 = __expf(v0 - m);
        float e1 = (lane + 32 < KNBR) ? __expf(v1 - m) : 0.f;
        float s = e0 + e1;
        #pragma unroll
        for (int off = 16; off >= 1; off >>= 1)
            s += __shfl_xor(s, off, 32);
        float inv = 1.f / s;
        scL[h][lane] = e0 * inv;
        if (lane + 32 < KNBR) scL[h][lane + 32] = e1 * inv;
    }
    __syncthreads();

    // phase 6: gather Fv (overwrite Gl) + Pbar = attn @ P
    for (int o = t; o < KNBR * CDIM; o += 256) {
        int k = o >> 7, c = o & 127;
        Gl[k][c] = Fv[idxl[k] * CDIM + c];
    }
    for (int o = t; o < HEADS * CDIM; o += 256) {
        int h = o >> 7, c = o & 127;
        float s = 0.f;
        #pragma unroll 8
        for (int k = 0; k < KNBR; ++k)
            s += scL[h][k] * Pl[k][c];
        Pbar[h][c] = s;
    }
    __syncthreads();

    // phase 7: ctx = attn @ Fv_gathered + Pbar @ wv_slice^T
    if (t < CDIM) {
        int c = t, h = c >> 4;
        float s = 0.f;
        #pragma unroll 8
        for (int k = 0; k < KNBR; ++k)
            s += scL[h][k] * Gl[k][c];
        const float4* wv4 = (const float4*)(wv + c * CDIM);
        const float4* pb4 = (const float4*)(&Pbar[h][0]);
        float s2 = 0.f;
        #pragma unroll 8
        for (int c4 = 0; c4 < CDIM / 4; ++c4) {
            float4 w = wv4[c4];
            float4 p = pb4[c4];
            s2 += p.x*w.x + p.y*w.y + p.z*w.z + p.w*w.w;
        }
        CTX[n * CDIM + c] = s + s2;
    }
}

// ---------------------------------------------------------------------------
// K3/K6: 128->128 GEMM + bias (+ optional residual) + LayerNorm (+ opt relu)
// Block 256 thr, 16 rows; thread owns col e=t&127, row-half rh=t>>7.
// ---------------------------------------------------------------------------
__global__ __launch_bounds__(256) void k_proj_ln(
    const float* __restrict__ X, const float* __restrict__ RES,
    const float* __restrict__ W, const float* __restrict__ B,
    const float* __restrict__ G, const float* __restrict__ LB,
    float* __restrict__ OUT, int N, int relu_out)
{
    __shared__ float xL[16][CDIM];
    __shared__ float aL[16][CDIM + 4];
    __shared__ float mu[16], rs[16];
    int row0 = blockIdx.x * 16;
    int t = threadIdx.x;
    for (int o = t; o < 16 * CDIM; o += 256) {
        int r = o >> 7, c = o & 127;
        int row = row0 + r;
        xL[r][c] = (row < N) ? X[row * CDIM + c] : 0.f;
    }
    __syncthreads();

    int e = t & 127, rh = t >> 7;
    const float4* W4 = (const float4*)(W + e * CDIM);
    float acc[8] = {0.f,0.f,0.f,0.f,0.f,0.f,0.f,0.f};
    #pragma unroll 8
    for (int c4 = 0; c4 < CDIM / 4; ++c4) {
        float4 w = W4[c4];
        #pragma unroll
        for (int i = 0; i < 8; ++i) {
            const float* x = &xL[rh * 8 + i][c4 * 4];
            acc[i] += x[0]*w.x + x[1]*w.y + x[2]*w.z + x[3]*w.w;
        }
    }
    float bv = B[e];
    #pragma unroll
    for (int i = 0; i < 8; ++i) {
        int r = rh * 8 + i, row = row0 + r;
        float a = acc[i] + bv;
        if (RES != nullptr && row < N) a += RES[row * CDIM + e];
        aL[r][e] = a;
    }
    __syncthreads();

    {   // LayerNorm stats: 16 threads per row, 8 elems each
        int r = t >> 4, j = t & 15;
        float s = 0.f;
        #pragma unroll
        for (int jj = 0; jj < 8; ++jj) s += aL[r][j * 8 + jj];
        #pragma unroll
        for (int off = 8; off >= 1; off >>= 1) s += __shfl_xor(s, off, 16);
        float mean = s * (1.f / 128.f);
        float v = 0.f;
        #pragma unroll
        for (int jj = 0; jj < 8; ++jj) {
            float d = aL[r][j * 8 + jj] - mean; v += d * d;
        }
        #pragma unroll
        for (int off = 8; off >= 1; off >>= 1) v += __shfl_xor(v, off, 16);
        if (j == 0) { mu[r] = mean; rs[r] = rsqrtf(v * (1.f / 128.f) + 1e-5f); }
    }
    __syncthreads();

    for (int o = t; o < 16 * CDIM; o += 256) {
        int r = o >> 7, c = o & 127;
        int row = row0 + r;
        if (row < N) {
            float y = (aL[r][c] - mu[r]) * rs[r] * G[c] + LB[c];
            if (relu_out) y = fmaxf(y, 0.f);
            OUT[row * CDIM + c] = y;
        }
    }
}

// ---------------------------------------------------------------------------
// K4: ff1: hid = relu(x1 @ W1^T + b1), 128 -> 256. Block 256 thr, 8 rows.
// ---------------------------------------------------------------------------
__global__ __launch_bounds__(256) void k_ff1(
    const float* __restrict__ X, const float* __restrict__ W,
    const float* __restrict__ B, float* __restrict__ HID, int N)
{
    __shared__ float xL[8][CDIM];
    int row0 = blockIdx.x * 8;
    int t = threadIdx.x;
    for (int o = t; o < 8 * CDIM; o += 256) {
        int r = o >> 7, c = o & 127;
        int row = row0 + r;
        xL[r][c] = (row < N) ? X[row * CDIM + c] : 0.f;
    }
    __syncthreads();

    int e = t;  // 0..255
    const float4* W4 = (const float4*)(W + e * CDIM);
    float acc[8] = {0.f,0.f,0.f,0.f,0.f,0.f,0.f,0.f};
    #pragma unroll 8
    for (int c4 = 0; c4 < CDIM / 4; ++c4) {
        float4 w = W4[c4];
        #pragma unroll
        for (int r = 0; r < 8; ++r) {
            const float* x = &xL[r][c4 * 4];
            acc[r] += x[0]*w.x + x[1]*w.y + x[2]*w.z + x[3]*w.w;
        }
    }
    float bv = B[e];
    #pragma unroll
    for (int r = 0; r < 8; ++r) {
        int row = row0 + r;
        if (row < N) HID[row * FFDIM + e] = fmaxf(acc[r] + bv, 0.f);
    }
}

// ---------------------------------------------------------------------------
// K5: x2 = LN(x1 + hid @ W2^T + b2), 256 -> 128.
// ---------------------------------------------------------------------------
__global__ __launch_bounds__(256) void k_ff2_ln(
    const float* __restrict__ HID, const float* __restrict__ RES,
    const float* __restrict__ W, const float* __restrict__ B,
    const float* __restrict__ G, const float* __restrict__ LB,
    float* __restrict__ OUT, int N)
{
    __shared__ float xL[16][FFDIM];
    __shared__ float aL[16][CDIM + 4];
    __shared__ float mu[16], rs[16];
    int row0 = blockIdx.x * 16;
    int t = threadIdx.x;
    for (int o = t; o < 16 * FFDIM; o += 256) {
        int r = o >> 8, c = o & 255;
        int row = row0 + r;
        xL[r][c] = (row < N) ? HID[row * FFDIM + c] : 0.f;
    }
    __syncthreads();

    int e = t & 127, rh = t >> 7;
    const float4* W4 = (const float4*)(W + e * FFDIM);
    float acc[8] = {0.f,0.f,0.f,0.f,0.f,0.f,0.f,0.f};
    #pragma unroll 8
    for (int c4 = 0; c4 < FFDIM / 4; ++c4) {
        float4 w = W4[c4];
        #pragma unroll
        for (int i = 0; i < 8; ++i) {
            const float* x = &xL[rh * 8 + i][c4 * 4];
            acc[i] += x[0]*w.x + x[1]*w.y + x[2]*w.z + x[3]*w.w;
        }
    }
    float bv = B[e];
    #pragma unroll
    for (int i = 0; i < 8; ++i) {
        int r = rh * 8 + i, row = row0 + r;
        float a = acc[i] + bv;
        if (row < N) a += RES[row * CDIM + e];
        aL[r][e] = a;
    }
    __syncthreads();

    {
        int r = t >> 4, j = t & 15;
        float s = 0.f;
        #pragma unroll
        for (int jj = 0; jj < 8; ++jj) s += aL[r][j * 8 + jj];
        #pragma unroll
        for (int off = 8; off >= 1; off >>= 1) s += __shfl_xor(s, off, 16);
        float mean = s * (1.f / 128.f);
        float v = 0.f;
        #pragma unroll
        for (int jj = 0; jj < 8; ++jj) {
            float d = aL[r][j * 8 + jj] - mean; v += d * d;
        }
        #pragma unroll
        for (int off = 8; off >= 1; off >>= 1) v += __shfl_xor(v, off, 16);
        if (j == 0) { mu[r] = mean; rs[r] = rsqrtf(v * (1.f / 128.f) + 1e-5f); }
    }
    __syncthreads();

    for (int o = t; o < 16 * CDIM; o += 256) {
        int r = o >> 7, c = o & 127;
        int row = row0 + r;
        if (row < N)
            OUT[row * CDIM + c] = (aL[r][c] - mu[r]) * rs[r] * G[c] + LB[c];
    }
}

// ---------------------------------------------------------------------------
extern "C" void kernel_launch(void* const* d_in, const int* in_sizes, int n_in,
                              void* d_out, int out_size, void* d_ws, size_t ws_size,
                              hipStream_t stream)
{
    const float* F      = (const float*)d_in[0];
    const float* coords = (const float*)d_in[1];
    const int*   kidx   = (const int*)d_in[2];
    const void*  kmask  = d_in[3];
    const float* ipw    = (const float*)d_in[4];
    const float* ipb    = (const float*)d_in[5];
    const float* opw    = (const float*)d_in[6];
    const float* opb    = (const float*)d_in[7];
    const float* kpw    = (const float*)d_in[8];
    const float* kpb    = (const float*)d_in[9];
    const float* ln1g   = (const float*)d_in[10];
    const float* ln1b   = (const float*)d_in[11];
    const float* ln2g   = (const float*)d_in[12];
    const float* ln2b   = (const float*)d_in[13];
    const float* w1     = (const float*)d_in[14];
    const float* b1     = (const float*)d_in[15];
    const float* w2     = (const float*)d_in[16];
    const float* b2     = (const float*)d_in[17];
    const float* ow     = (const float*)d_in[18];
    const float* ob     = (const float*)d_in[19];
    const float* ln3g   = (const float*)d_in[20];
    const float* ln3b   = (const float*)d_in[21];

    int N = in_sizes[0] / CDIM;
    size_t NC = (size_t)N * CDIM;

    float* ws  = (float*)d_ws;
    float* Q   = ws;                 // N*128
    float* Fk  = ws + NC;            // N*128
    float* Fv  = ws + 2 * NC;        // N*128
    float* CTX = ws + 3 * NC;        // N*128
    float* X1  = Q;                  // reuse (Q dead after attention)
    float* HID = ws + NC;            // N*256, over Fk+Fv (dead after attention)
    float* X2  = CTX;                // reuse (CTX dead after K3)
    int* mflag = (int*)(ws + 4 * NC);

    const float* wk = ipw + CDIM * CDIM;
    const float* wv = ipw + 2 * CDIM * CDIM;

    hipMemsetAsync(mflag, 0, sizeof(int), stream);
    int nwords = (N * KNBR) / 4;   // N*KNBR bytes, in-bounds for u8 or i32 storage
    k_mask_probe<<<256, 256, 0, stream>>>((const unsigned int*)kmask, nwords, mflag);

    k_qkv<<<(N + 7) / 8, 384, 0, stream>>>(F, ipw, ipb, Q, Fk, Fv, N);
    k_attn<<<N, 256, 0, stream>>>(coords, kidx, (const u8*)kmask,
                                  (const int*)kmask, mflag, Q, Fk, Fv,
                                  wk, wv, kpw, kpb, CTX);
    k_proj_ln<<<(N + 15) / 16, 256, 0, stream>>>(CTX, F, opw, opb,
                                                 ln1g, ln1b, X1, N, 0);
    k_ff1<<<(N + 7) / 8, 256, 0, stream>>>(X1, w1, b1, HID, N);
    k_ff2_ln<<<(N + 15) / 16, 256, 0, stream>>>(HID, X1, w2, b2,
                                                ln2g, ln2b, X2, N);
    k_proj_ln<<<(N + 15) / 16, 256, 0, stream>>>(X2, nullptr, ow, ob,
                                                 ln3g, ln3b, (float*)d_out, N, 1);
}

// Round 4
// 1222.989 us; speedup vs baseline: 1.6503x; 1.6503x over previous
//
#include <hip/hip_runtime.h>
#include <stdint.h>

typedef unsigned char u8;
typedef unsigned int u32;

#define CDIM  128
#define KNBR  48
#define HEADS 8
#define DHEAD 16
#define FFDIM 256
#define OUTD  128

// ---------------------------------------------------------------------------
// K0: probe key_mask storage (int32 vs u8 bool). flag=1 -> u8 storage.
// ---------------------------------------------------------------------------
__global__ void k_mask_probe(const u32* __restrict__ mw, int nwords,
                             int* __restrict__ flag)
{
    u32 any = 0;
    for (int j = blockIdx.x * blockDim.x + threadIdx.x; j < nwords;
         j += gridDim.x * blockDim.x)
        any |= mw[j] & 0xFFFFFF00u;
    if (any) atomicOr(flag, 1);
}

// ---------------------------------------------------------------------------
// K1: QKV projection.  QKV = F @ in_proj_w^T + in_proj_b, split into Q/Fk/Fv.
// ---------------------------------------------------------------------------
__global__ __launch_bounds__(384) void k_qkv(
    const float* __restrict__ F, const float* __restrict__ W,
    const float* __restrict__ B,
    float* __restrict__ Q, float* __restrict__ Fk, float* __restrict__ Fv, int N)
{
    __shared__ float xL[8][CDIM];
    int row0 = blockIdx.x * 8;
    int t = threadIdx.x;
    for (int o = t; o < 8 * CDIM; o += 384) {
        int r = o >> 7, c = o & 127;
        int row = row0 + r;
        xL[r][c] = (row < N) ? F[row * CDIM + c] : 0.f;
    }
    __syncthreads();

    int e = t;  // 0..383
    const float4* W4 = (const float4*)(W + e * CDIM);
    float acc[8] = {0.f,0.f,0.f,0.f,0.f,0.f,0.f,0.f};
    #pragma unroll 8
    for (int c4 = 0; c4 < CDIM / 4; ++c4) {
        float4 w = W4[c4];
        #pragma unroll
        for (int r = 0; r < 8; ++r) {
            const float* x = &xL[r][c4 * 4];
            acc[r] += x[0]*w.x + x[1]*w.y + x[2]*w.z + x[3]*w.w;
        }
    }
    float bv = B[e];
    float* dst; int eo;
    if (e < 128)      { dst = Q;  eo = e; }
    else if (e < 256) { dst = Fk; eo = e - 128; }
    else              { dst = Fv; eo = e - 256; }
    #pragma unroll
    for (int r = 0; r < 8; ++r) {
        int row = row0 + r;
        if (row < N) dst[row * CDIM + eo] = acc[r] + bv;
    }
}

// ---------------------------------------------------------------------------
// K2: attention, one block (256 thr) per query voxel. All-f32 math (score
// precision requires it: scores are O(100) from the pos-emb path).
// No LDS staging of gathered Fk/Fv: gathers are fused into the consuming
// loops with coalesced row reads.  LDS = 32448 B -> 5 blocks/CU (62.5% cap).
//   score[h,k] = ( q_h . Fk[idx_k]_h  +  qw[h,:] . P[k,:] ) / 4
//   ctx[c]     = sum_k a[h,k] Fv[idx_k][c]  +  Pbar[h,:] . wv[c,:]
// ---------------------------------------------------------------------------
__global__ __launch_bounds__(256, 5) void k_attn(
    const float* __restrict__ coords, const int* __restrict__ kidx,
    const u8* __restrict__ kmask_u8, const int* __restrict__ kmask_i32,
    const int* __restrict__ maskflag,
    const float* __restrict__ Q, const float* __restrict__ Fk,
    const float* __restrict__ Fv,
    const float* __restrict__ wk, const float* __restrict__ wv,
    const float* __restrict__ kpw, const float* __restrict__ kpb,
    float* __restrict__ CTX)
{
    // manual LDS layout (bytes):
    //   Pl   [48][132] f32   @ 0      .. 25344
    //   qwl  [8][132]  f32   @ 25344  .. 29568   (qw; aliased by Pbar in E/F)
    //   scL  [8][48]   f32   @ 29568  .. 31104
    //   Ql   [128]     f32   @ 31104  .. 31616   } aliased by pc[256] in F
    //   rel  [48][3]   f32   @ 31616  .. 32192   } (Ql/rel dead by then)
    //   idxl [48]      i32   @ 32192  .. 32384
    //   mskl [48]      u8    @ 32384  .. 32448
    __shared__ __align__(16) u8 SM[32448];
    float* Pl   = (float*)(SM);
    float* qwl  = (float*)(SM + 25344);
    float* scL  = (float*)(SM + 29568);
    float* Ql   = (float*)(SM + 31104);
    float* pc   = (float*)(SM + 31104);
    float* rel  = (float*)(SM + 31616);
    int*   idxl = (int*)  (SM + 32192);
    u8*    mskl = (u8*)   (SM + 32384);

    int n = blockIdx.x;
    int t = threadIdx.x;

    // ---- phase A: indices / mask / rel coords / q row ----
    if (t < KNBR) {
        int idx = kidx[n * KNBR + t];
        idxl[t] = idx;
        mskl[t] = maskflag[0] ? kmask_u8[n * KNBR + t]
                              : (u8)kmask_i32[n * KNBR + t];
        rel[t * 3 + 0] = coords[idx * 3 + 0] - coords[n * 3 + 0];
        rel[t * 3 + 1] = coords[idx * 3 + 1] - coords[n * 3 + 1];
        rel[t * 3 + 2] = coords[idx * 3 + 2] - coords[n * 3 + 2];
    } else if (t >= 128) {
        Ql[t - 128] = Q[n * CDIM + (t - 128)];
    }
    __syncthreads();

    // ---- phase B: qw[h][:] = q_h @ wk_h   and   P = relu(rel.kpw^T + kpb) ----
    {
        int h = t >> 5, c4 = t & 31;
        float a0 = 0.f, a1 = 0.f, a2 = 0.f, a3 = 0.f;
        const float* qh = Ql + h * DHEAD;
        #pragma unroll
        for (int d = 0; d < DHEAD; ++d) {
            float q = qh[d];
            float4 w = *(const float4*)(wk + (size_t)(h * DHEAD + d) * CDIM + c4 * 4);
            a0 += q * w.x; a1 += q * w.y; a2 += q * w.z; a3 += q * w.w;
        }
        *(float4*)(qwl + h * 132 + c4 * 4) = make_float4(a0, a1, a2, a3);
    }
    #pragma unroll
    for (int it = 0; it < 6; ++it) {
        int o = t + it * 256;                 // 1536 = 48 k x 32 c-quads
        int k = o >> 5, c4 = o & 31;
        float r0 = rel[k * 3], r1 = rel[k * 3 + 1], r2 = rel[k * 3 + 2];
        const float4* kw = (const float4*)(kpw + c4 * 12);
        float4 wa = kw[0], wb = kw[1], wc = kw[2];
        float4 bb = ((const float4*)kpb)[c4];
        float p0 = fmaxf(bb.x + r0 * wa.x + r1 * wa.y + r2 * wa.z, 0.f);
        float p1 = fmaxf(bb.y + r0 * wa.w + r1 * wb.x + r2 * wb.y, 0.f);
        float p2 = fmaxf(bb.z + r0 * wb.z + r1 * wb.w + r2 * wc.x, 0.f);
        float p3 = fmaxf(bb.w + r0 * wc.y + r1 * wc.z + r2 * wc.w, 0.f);
        *(float4*)(Pl + k * 132 + c4 * 4) = make_float4(p0, p1, p2, p3);
    }
    __syncthreads();

    // ---- phase C: scores (fused coalesced Fk gather: 8 lanes = 1 row) ----
    for (int o = t; o < HEADS * KNBR; o += 256) {
        int k = o >> 3, h = o & 7;
        const float* qh = Ql + h * DHEAD;
        const float4* fk = (const float4*)(Fk + (size_t)idxl[k] * CDIM + h * DHEAD);
        float4 f0 = fk[0], f1 = fk[1], f2 = fk[2], f3 = fk[3];
        float s = qh[0]*f0.x + qh[1]*f0.y + qh[2]*f0.z + qh[3]*f0.w
                + qh[4]*f1.x + qh[5]*f1.y + qh[6]*f1.z + qh[7]*f1.w
                + qh[8]*f2.x + qh[9]*f2.y + qh[10]*f2.z + qh[11]*f2.w
                + qh[12]*f3.x + qh[13]*f3.y + qh[14]*f3.z + qh[15]*f3.w;
        const float4* qw4 = (const float4*)(qwl + h * 132);
        const float4* pl4 = (const float4*)(Pl + k * 132);
        #pragma unroll 8
        for (int j = 0; j < 32; ++j) {
            float4 a = qw4[j], b = pl4[j];
            s += a.x*b.x + a.y*b.y + a.z*b.z + a.w*b.w;
        }
        scL[h * KNBR + k] = mskl[k] ? -1e30f : s * 0.25f;
    }
    __syncthreads();

    // ---- phase D: softmax (32 lanes per head) ----
    {
        int h = t >> 5, lane = t & 31;
        float* sc = scL + h * KNBR;
        float v0 = sc[lane];
        float v1 = (lane < KNBR - 32) ? sc[lane + 32] : -1e30f;
        float m = fmaxf(v0, v1);
        #pragma unroll
        for (int off = 16; off >= 1; off >>= 1)
            m = fmaxf(m, __shfl_xor(m, off, 32));
        float e0 = __expf(v0 - m);
        float e1 = (lane < KNBR - 32) ? __expf(v1 - m) : 0.f;
        float s = e0 + e1;
        #pragma unroll
        for (int off = 16; off >= 1; off >>= 1)
            s += __shfl_xor(s, off, 32);
        float inv = 1.f / s;
        sc[lane] = e0 * inv;
        if (lane < KNBR - 32) sc[lane + 32] = e1 * inv;
    }
    __syncthreads();

    // ---- phase E: Pbar[h][:] = attn[h,:] @ P  (overwrites qwl) ----
    {
        int h = t >> 5, c4 = t & 31;
        const float* sc = scL + h * KNBR;
        float a0 = 0.f, a1 = 0.f, a2 = 0.f, a3 = 0.f;
        #pragma unroll 8
        for (int k = 0; k < KNBR; ++k) {
            float p = sc[k];
            float4 pv = *(const float4*)(Pl + k * 132 + c4 * 4);
            a0 += p * pv.x; a1 += p * pv.y; a2 += p * pv.z; a3 += p * pv.w;
        }
        *(float4*)(qwl + h * 132 + c4 * 4) = make_float4(a0, a1, a2, a3);
    }
    __syncthreads();

    // ---- phase F: ctx = attn @ Fv (fused coalesced gather) + Pbar . wv ----
    {
        int c = t & 127, half = t >> 7;
        int h = c >> 4;
        const float* sc = scL + h * KNBR;
        float acc = 0.f;
        #pragma unroll 4
        for (int kk = 0; kk < 24; ++kk) {
            int k = half * 24 + kk;
            acc += sc[k] * Fv[(size_t)idxl[k] * CDIM + c];
        }
        const float4* wr = (const float4*)(wv + (size_t)c * CDIM) + half * 16;
        const float4* pb = (const float4*)(qwl + h * 132) + half * 16;
        #pragma unroll 4
        for (int j = 0; j < 16; ++j) {
            float4 w = wr[j], p = pb[j];
            acc += w.x*p.x + w.y*p.y + w.z*p.z + w.w*p.w;
        }
        pc[half * 128 + c] = acc;
    }
    __syncthreads();
    if (t < CDIM) CTX[n * CDIM + t] = pc[t] + pc[128 + t];
}

// ---------------------------------------------------------------------------
// K3/K6: 128->128 GEMM + bias (+ optional residual) + LayerNorm (+ opt relu)
// ---------------------------------------------------------------------------
__global__ __launch_bounds__(256) void k_proj_ln(
    const float* __restrict__ X, const float* __restrict__ RES,
    const float* __restrict__ W, const float* __restrict__ B,
    const float* __restrict__ G, const float* __restrict__ LB,
    float* __restrict__ OUT, int N, int relu_out)
{
    __shared__ float xL[16][CDIM];
    __shared__ float aL[16][CDIM + 4];
    __shared__ float mu[16], rs[16];
    int row0 = blockIdx.x * 16;
    int t = threadIdx.x;
    for (int o = t; o < 16 * CDIM; o += 256) {
        int r = o >> 7, c = o & 127;
        int row = row0 + r;
        xL[r][c] = (row < N) ? X[row * CDIM + c] : 0.f;
    }
    __syncthreads();

    int e = t & 127, rh = t >> 7;
    const float4* W4 = (const float4*)(W + e * CDIM);
    float acc[8] = {0.f,0.f,0.f,0.f,0.f,0.f,0.f,0.f};
    #pragma unroll 8
    for (int c4 = 0; c4 < CDIM / 4; ++c4) {
        float4 w = W4[c4];
        #pragma unroll
        for (int i = 0; i < 8; ++i) {
            const float* x = &xL[rh * 8 + i][c4 * 4];
            acc[i] += x[0]*w.x + x[1]*w.y + x[2]*w.z + x[3]*w.w;
        }
    }
    float bv = B[e];
    #pragma unroll
    for (int i = 0; i < 8; ++i) {
        int r = rh * 8 + i, row = row0 + r;
        float a = acc[i] + bv;
        if (RES != nullptr && row < N) a += RES[row * CDIM + e];
        aL[r][e] = a;
    }
    __syncthreads();

    {
        int r = t >> 4, j = t & 15;
        float s = 0.f;
        #pragma unroll
        for (int jj = 0; jj < 8; ++jj) s += aL[r][j * 8 + jj];
        #pragma unroll
        for (int off = 8; off >= 1; off >>= 1) s += __shfl_xor(s, off, 16);
        float mean = s * (1.f / 128.f);
        float v = 0.f;
        #pragma unroll
        for (int jj = 0; jj < 8; ++jj) {
            float d = aL[r][j * 8 + jj] - mean; v += d * d;
        }
        #pragma unroll
        for (int off = 8; off >= 1; off >>= 1) v += __shfl_xor(v, off, 16);
        if (j == 0) { mu[r] = mean; rs[r] = rsqrtf(v * (1.f / 128.f) + 1e-5f); }
    }
    __syncthreads();

    for (int o = t; o < 16 * CDIM; o += 256) {
        int r = o >> 7, c = o & 127;
        int row = row0 + r;
        if (row < N) {
            float y = (aL[r][c] - mu[r]) * rs[r] * G[c] + LB[c];
            if (relu_out) y = fmaxf(y, 0.f);
            OUT[row * CDIM + c] = y;
        }
    }
}

// ---------------------------------------------------------------------------
// K4: ff1: hid = relu(x1 @ W1^T + b1), 128 -> 256.
// ---------------------------------------------------------------------------
__global__ __launch_bounds__(256) void k_ff1(
    const float* __restrict__ X, const float* __restrict__ W,
    const float* __restrict__ B, float* __restrict__ HID, int N)
{
    __shared__ float xL[8][CDIM];
    int row0 = blockIdx.x * 8;
    int t = threadIdx.x;
    for (int o = t; o < 8 * CDIM; o += 256) {
        int r = o >> 7, c = o & 127;
        int row = row0 + r;
        xL[r][c] = (row < N) ? X[row * CDIM + c] : 0.f;
    }
    __syncthreads();

    int e = t;
    const float4* W4 = (const float4*)(W + e * CDIM);
    float acc[8] = {0.f,0.f,0.f,0.f,0.f,0.f,0.f,0.f};
    #pragma unroll 8
    for (int c4 = 0; c4 < CDIM / 4; ++c4) {
        float4 w = W4[c4];
        #pragma unroll
        for (int r = 0; r < 8; ++r) {
            const float* x = &xL[r][c4 * 4];
            acc[r] += x[0]*w.x + x[1]*w.y + x[2]*w.z + x[3]*w.w;
        }
    }
    float bv = B[e];
    #pragma unroll
    for (int r = 0; r < 8; ++r) {
        int row = row0 + r;
        if (row < N) HID[row * FFDIM + e] = fmaxf(acc[r] + bv, 0.f);
    }
}

// ---------------------------------------------------------------------------
// K5: x2 = LN(x1 + hid @ W2^T + b2), 256 -> 128.
// ---------------------------------------------------------------------------
__global__ __launch_bounds__(256) void k_ff2_ln(
    const float* __restrict__ HID, const float* __restrict__ RES,
    const float* __restrict__ W, const float* __restrict__ B,
    const float* __restrict__ G, const float* __restrict__ LB,
    float* __restrict__ OUT, int N)
{
    __shared__ float xL[16][FFDIM];
    __shared__ float aL[16][CDIM + 4];
    __shared__ float mu[16], rs[16];
    int row0 = blockIdx.x * 16;
    int t = threadIdx.x;
    for (int o = t; o < 16 * FFDIM; o += 256) {
        int r = o >> 8, c = o & 255;
        int row = row0 + r;
        xL[r][c] = (row < N) ? HID[row * FFDIM + c] : 0.f;
    }
    __syncthreads();

    int e = t & 127, rh = t >> 7;
    const float4* W4 = (const float4*)(W + e * FFDIM);
    float acc[8] = {0.f,0.f,0.f,0.f,0.f,0.f,0.f,0.f};
    #pragma unroll 8
    for (int c4 = 0; c4 < FFDIM / 4; ++c4) {
        float4 w = W4[c4];
        #pragma unroll
        for (int i = 0; i < 8; ++i) {
            const float* x = &xL[rh * 8 + i][c4 * 4];
            acc[i] += x[0]*w.x + x[1]*w.y + x[2]*w.z + x[3]*w.w;
        }
    }
    float bv = B[e];
    #pragma unroll
    for (int i = 0; i < 8; ++i) {
        int r = rh * 8 + i, row = row0 + r;
        float a = acc[i] + bv;
        if (row < N) a += RES[row * CDIM + e];
        aL[r][e] = a;
    }
    __syncthreads();

    {
        int r = t >> 4, j = t & 15;
        float s = 0.f;
        #pragma unroll
        for (int jj = 0; jj < 8; ++jj) s += aL[r][j * 8 + jj];
        #pragma unroll
        for (int off = 8; off >= 1; off >>= 1) s += __shfl_xor(s, off, 16);
        float mean = s * (1.f / 128.f);
        float v = 0.f;
        #pragma unroll
        for (int jj = 0; jj < 8; ++jj) {
            float d = aL[r][j * 8 + jj] - mean; v += d * d;
        }
        #pragma unroll
        for (int off = 8; off >= 1; off >>= 1) v += __shfl_xor(v, off, 16);
        if (j == 0) { mu[r] = mean; rs[r] = rsqrtf(v * (1.f / 128.f) + 1e-5f); }
    }
    __syncthreads();

    for (int o = t; o < 16 * CDIM; o += 256) {
        int r = o >> 7, c = o & 127;
        int row = row0 + r;
        if (row < N)
            OUT[row * CDIM + c] = (aL[r][c] - mu[r]) * rs[r] * G[c] + LB[c];
    }
}

// ---------------------------------------------------------------------------
extern "C" void kernel_launch(void* const* d_in, const int* in_sizes, int n_in,
                              void* d_out, int out_size, void* d_ws, size_t ws_size,
                              hipStream_t stream)
{
    const float* F      = (const float*)d_in[0];
    const float* coords = (const float*)d_in[1];
    const int*   kidx   = (const int*)d_in[2];
    const void*  kmask  = d_in[3];
    const float* ipw    = (const float*)d_in[4];
    const float* ipb    = (const float*)d_in[5];
    const float* opw    = (const float*)d_in[6];
    const float* opb    = (const float*)d_in[7];
    const float* kpw    = (const float*)d_in[8];
    const float* kpb    = (const float*)d_in[9];
    const float* ln1g   = (const float*)d_in[10];
    const float* ln1b   = (const float*)d_in[11];
    const float* ln2g   = (const float*)d_in[12];
    const float* ln2b   = (const float*)d_in[13];
    const float* w1     = (const float*)d_in[14];
    const float* b1     = (const float*)d_in[15];
    const float* w2     = (const float*)d_in[16];
    const float* b2     = (const float*)d_in[17];
    const float* ow     = (const float*)d_in[18];
    const float* ob     = (const float*)d_in[19];
    const float* ln3g   = (const float*)d_in[20];
    const float* ln3b   = (const float*)d_in[21];

    int N = in_sizes[0] / CDIM;
    size_t NC = (size_t)N * CDIM;

    float* ws  = (float*)d_ws;
    float* Q   = ws;                 // N*128
    float* Fk  = ws + NC;            // N*128
    float* Fv  = ws + 2 * NC;        // N*128
    float* CTX = ws + 3 * NC;        // N*128
    float* X1  = Q;                  // reuse (Q dead after attention)
    float* HID = ws + NC;            // N*256, over Fk+Fv (dead after attention)
    float* X2  = CTX;                // reuse (CTX dead after K3)
    int* mflag = (int*)(ws + 4 * NC);

    const float* wk = ipw + CDIM * CDIM;
    const float* wv = ipw + 2 * CDIM * CDIM;

    hipMemsetAsync(mflag, 0, sizeof(int), stream);
    int nwords = (N * KNBR) / 4;
    k_mask_probe<<<256, 256, 0, stream>>>((const u32*)kmask, nwords, mflag);

    k_qkv<<<(N + 7) / 8, 384, 0, stream>>>(F, ipw, ipb, Q, Fk, Fv, N);
    k_attn<<<N, 256, 0, stream>>>(coords, kidx, (const u8*)kmask,
                                  (const int*)kmask, mflag, Q, Fk, Fv,
                                  wk, wv, kpw, kpb, CTX);
    k_proj_ln<<<(N + 15) / 16, 256, 0, stream>>>(CTX, F, opw, opb,
                                                 ln1g, ln1b, X1, N, 0);
    k_ff1<<<(N + 7) / 8, 256, 0, stream>>>(X1, w1, b1, HID, N);
    k_ff2_ln<<<(N + 15) / 16, 256, 0, stream>>>(HID, X1, w2, b2,
                                                ln2g, ln2b, X2, N);
    k_proj_ln<<<(N + 15) / 16, 256, 0, stream>>>(X2, nullptr, ow, ob,
                                                 ln3g, ln3b, (float*)d_out, N, 1);
}